// Round 13
// baseline (122.709 us; speedup 1.0000x reference)
//
#include <hip/hip_runtime.h>
#include <stdint.h>

typedef float v4f __attribute__((ext_vector_type(4)));
typedef int   v8i __attribute__((ext_vector_type(8)));
typedef unsigned long long u64;

#define PEX_STRIDE 1156
#define WS_IMG8   0
#define WS_BFRAG  1048576
#define WS_PEX    1064960
#define WS_RESULT 9994240
#define WS_CAND   14188544

__device__ inline unsigned char f32_to_e4m3(float v) {
    if (!(v > 0.0f)) return 0;
    if (v >= 448.0f) return 0x7e;
    if (v < 0.015625f) {                       // subnormal: m * 2^-9
        int m = (int)(v * 512.0f + 0.5f);
        if (m > 7) return 0x08;
        return (unsigned char)m;
    }
    unsigned int u = __float_as_uint(v) + 0x00080000u;  // round into bit 20
    int e = (int)((u >> 23) & 0xff) - 127;
    int m3 = (int)(u >> 20) & 7;
    int e8 = e + 7;
    if (e8 >= 16) return 0x7e;
    return (unsigned char)((e8 << 3) | m3);
}

// Fused front kernel.
// blocks [0,1024): wrapped row prefix sums + fp8 image emit (row L1-hot)
// blocks [1024,2080): zero d_out
// blocks [2080,2144): A-fragment psf table for the K=128 MX MFMA:
//   abuf[kb4][lane][b] fp8 = psf[z][a][b]*cos(2pi(a+b-32)/1024)*1024,
//   z=lane&15, a=4*kb4+(lane>>4), b=0..31; also zeroes cnt[0].
__global__ void k_pex(const float* __restrict__ img, float* __restrict__ pex,
                      uint32_t* __restrict__ img8, const float* __restrict__ psf,
                      unsigned char* __restrict__ bf, unsigned int* cnt,
                      float4* __restrict__ out, int n4) {
    __shared__ float wtot[4];
    int blk = blockIdx.x, t = threadIdx.x;
    if (blk >= 1024) {
        if (blk < 2080) {
            int i = (blk - 1024) * 256 + t;
            if (i < n4) { float4 z; z.x = z.y = z.z = z.w = 0.f; out[i] = z; }
        } else {
            int u = (blk - 2080) * 256 + t;   // 16384 = 8 kb4 x 64 lanes x 32 B
            if (u == 0) cnt[0] = 0u;
            int kb4 = u >> 11; int l = (u >> 5) & 63; int b = u & 31;
            int z = l & 15; int a = kb4 * 4 + (l >> 4);
            float p = psf[z * 1024 + a * 32 + b];
            float c = cosf((float)(a + b - 32) * (6.283185307179586f / 1024.0f));
            bf[u] = f32_to_e4m3(p * c * 1024.0f);
        }
        return;
    }
    int r = blk;
    const float* row = img + r * 1024;
    float s[5];
    float acc = 0.f;
    int base = t * 5;
    #pragma unroll
    for (int j = 0; j < 5; j++) {
        int c = base + j;
        float v = (c < 1152) ? row[(c - 64) & 1023] : 0.f;
        acc += v; s[j] = acc;
    }
    float sc = acc;
    int lane = t & 63, w = t >> 6;
    #pragma unroll
    for (int off = 1; off < 64; off <<= 1) {
        float v = __shfl_up(sc, off, 64);
        if (lane >= off) sc += v;
    }
    if (lane == 63) wtot[w] = sc;
    __syncthreads();
    float wbase = 0.f;
    #pragma unroll
    for (int i = 0; i < 3; i++) if (i < w) wbase += wtot[i];
    float excl = wbase + (sc - acc);
    float* prow = pex + r * PEX_STRIDE;
    if (t == 0) prow[0] = 0.f;
    #pragma unroll
    for (int j = 0; j < 5; j++) {
        int c = base + j;
        if (c < 1152) prow[c + 1] = excl + s[j];
    }
    float4 v4 = *(const float4*)(row + 4 * t);
    img8[r * 256 + t] = (uint32_t)f32_to_e4m3(v4.x)
                      | ((uint32_t)f32_to_e4m3(v4.y) << 8)
                      | ((uint32_t)f32_to_e4m3(v4.z) << 16)
                      | ((uint32_t)f32_to_e4m3(v4.w) << 24);
}

// build MX MFMA B operand from 4 u64 (constant-index inserts: register-only)
__device__ inline v8i packb(u64 a, u64 b, u64 c, u64 d) {
    v8i v;
    v[0] = (int)(unsigned int)a;  v[1] = (int)(unsigned int)(a >> 32);
    v[2] = (int)(unsigned int)b;  v[3] = (int)(unsigned int)(b >> 32);
    v[4] = (int)(unsigned int)c;  v[5] = (int)(unsigned int)(c >> 32);
    v[6] = (int)(unsigned int)d;  v[7] = (int)(unsigned int)(d >> 32);
    return v;
}

__device__ inline float redz(v4f a) {   // z-max over 16 z (4 regs + cross-g)
    float m = fmaxf(fmaxf(a.x, a.y), fmaxf(a.z, a.w));
    m = fmaxf(m, __shfl_xor(m, 16, 64));
    m = fmaxf(m, __shfl_xor(m, 32, 64));
    return m;
}

// MFMA conv (MX fp8 K=128): single-copy LDS staging + register funnel shifts.
// r12 PMC: with __launch_bounds__(512,4) the compiler clamped VGPR at 64 —
// but the 16 live v4f accumulators alone need 64 VGPR -> full accumulator
// spill to scratch (WRITE_SIZE 23.5MB vs 4MB true, FETCH +17MB, 50us).
// THIS ROUND: bounds (512,2) -> 128-VGPR budget (r10 precedent: VGPR 88, no
// clamp). Demand ~110: accs 64 + window 12 + funnels 10 + misc. 2 blocks/CU,
// 4 waves/SIMD. Everything else byte-identical to r12: stage tile ONCE (760
// coalesced u64 writes, 10-u64 row stride -> conflict-free b128 reads),
// byte-shifts as register funnels, 8 waves = 4 rowgrps x 2 chain-halves,
// 128 MFMAs/wave at the MX rate.
__global__ __launch_bounds__(512, 2) void k_conv(
    const unsigned long long* __restrict__ img64,
    const unsigned char* __restrict__ bfrag,
    const float* __restrict__ pex, float* __restrict__ result) {
    __shared__ ulonglong2 smv[95 * 5];     // [row][5x16B]; u64 0..7 used, 8..9 pad
    __shared__ float rbp[8][5][8];
    __shared__ float rbv[8][5];
    int tid = threadIdx.x;
    int wave = tid >> 6, lane = tid & 63;
    int b = blockIdx.x;
    int tr = b >> 5, tc = b & 31;
    int r0 = tr * 64, c0 = tc * 32;

    // fused bg partial sums (disk r=64 mean via pex prefix): 8x8 rows x 5
    // sampled cols = 40 lanes, dy-chunk of 16 per wave; j==127 predicated off.
    if (lane < 40) {
        int si = lane / 5, kc = lane - si * 5;
        int baserow = r0 + si * 8 + 3;
        int n = c0 + 8 * kc;
        int j0 = wave * 16;
        float acc = 0.f;
        #pragma unroll
        for (int u = 0; u < 16; u++) {
            int j = j0 + u;
            if (j < 127) {
                int dy = j - 63;
                int ady = dy < 0 ? -dy : dy;
                int w = (int)sqrtf((float)(4095 - ady * ady));
                const float* p = pex + ((baserow + dy) & 1023) * PEX_STRIDE + n;
                acc += p[65 + w] - p[64 - w];
            }
        }
        rbp[si][kc][wave] = acc;
    }

    // staging: 95 rows x 8 u64 (single copy — no shifted expansion)
    u64* smq = (u64*)smv;
    for (int u = tid; u < 760; u += 512) {
        int dr = u >> 3, j = u & 7;
        int row = (r0 + dr - 16) & 1023;
        int cbyte = (c0 - 16 + 8 * j) & 1023;
        smq[dr * 10 + j] = img64[row * 128 + (cbyte >> 3)];
    }
    __syncthreads();
    if (tid < 40) {
        int si = tid / 5, kc = tid - si * 5;
        float s = 0.f;
        #pragma unroll
        for (int h = 0; h < 8; h++) s += rbp[si][kc][h];
        const float kk = (float)(1.0 / (3.14159265358979323846 * 4096.0));
        rbv[si][kc] = 1.0f / ((s * kk + 1.0f) * 1024.0f);  // /1024 undoes psf scale
    }

    int rg = wave >> 1, h = wave & 1;         // row group, chain half
    int i0 = rg * 16;
    int nn = lane & 15, g = lane >> 4;
    const v8i* bfA = (const v8i*)(bfrag + lane * 32);   // A rows for this lane

    v4f acc0[8], acc1[8];                     // [sh] chains 2h, 2h+1
    #pragma unroll
    for (int s = 0; s < 8; s++) { acc0[s] = (v4f)0.f; acc1[s] = (v4f)0.f; }

    #pragma unroll
    for (int kb4 = 0; kb4 < 8; kb4++) {
        int lr = i0 + nn + g + 4 * kb4;       // local staged row 0..94
        const ulonglong2* rp = smv + lr * 5 + h;
        ulonglong2 p0 = rp[0], p1 = rp[1], p2 = rp[2];
        u64 w0 = p0.x, w1 = p0.y, w2 = p1.x, w3 = p1.y, w4 = p2.x, w5 = p2.y;
        v8i av = bfA[kb4 << 6];               // bfrag + kb4*2048 + lane*32
        #pragma unroll
        for (int sh = 0; sh < 8; sh++) {
            u64 S0, S1, S2, S3, S4;
            if (sh == 0) { S0 = w0; S1 = w1; S2 = w2; S3 = w3; S4 = w4; }
            else {
                const int sb = 8 * sh;
                S0 = (w0 >> sb) | (w1 << (64 - sb));
                S1 = (w1 >> sb) | (w2 << (64 - sb));
                S2 = (w2 >> sb) | (w3 << (64 - sb));
                S3 = (w3 >> sb) | (w4 << (64 - sb));
                S4 = (w4 >> sb) | (w5 << (64 - sb));
            }
            acc0[sh] = __builtin_amdgcn_mfma_scale_f32_16x16x128_f8f6f4(
                    av, packb(S0, S1, S2, S3), acc0[sh], 0, 0, 0,
                    0x7f7f7f7f, 0, 0x7f7f7f7f);
            acc1[sh] = __builtin_amdgcn_mfma_scale_f32_16x16x128_f8f6f4(
                    av, packb(S1, S2, S3, S4), acc1[sh], 0, 0, 0,
                    0x7f7f7f7f, 0, 0x7f7f7f7f);
        }
    }

    float zm0[8], zm1[8];
    #pragma unroll
    for (int sh = 0; sh < 8; sh++) { zm0[sh] = redz(acc0[sh]); zm1[sh] = redz(acc1[sh]); }
    __syncthreads();   // rbv ready

    // epilogue: lane (nn,g) stores row i0+nn, cols c0+16h+4g..+3 (16B float4)
    int sil = (i0 + nn) >> 3;
    int kc = 2 * h + (g >> 1);
    float rv0 = rbv[sil][kc], rv1 = rbv[sil][kc + 1];
    float drv = rv1 - rv0;
    float ov[4];
    #pragma unroll
    for (int t = 0; t < 4; t++) {
        float za = (g & 1) ? zm0[4 + t] : zm0[t];
        float zb = (g & 1) ? zm1[4 + t] : zm1[t];
        float z = (g & 2) ? zb : za;
        float fr = (float)(4 * (g & 1) + t) * 0.125f;
        ov[t] = z * (rv0 + fr * drv);
    }
    float4 o; o.x = ov[0]; o.y = ov[1]; o.z = ov[2]; o.w = ov[3];
    *(float4*)(result + (r0 + i0 + nn) * 1024 + c0 + 16 * h + 4 * g) = o;
}

// fused 32x32 stride-1 maxpool + candidate extraction, with fast reject.
__global__ __launch_bounds__(256) void k_maxcand(const float* __restrict__ result,
                                                 unsigned int* cnt,
                                                 unsigned long long* cand) {
    __shared__ float ls[95 * 96];
    __shared__ float hr[95 * 64];
    __shared__ float wmax[4];
    int bx = blockIdx.x & 15, by = blockIdx.x >> 4;
    int i0 = by * 64, j0 = bx * 64;
    int t = threadIdx.x;
    // fast reject: tile max over the 64x64 core (float4 loads)
    const float4* cb4 = (const float4*)(result + i0 * 1024 + j0);
    float mx = -3.4e38f;
    #pragma unroll
    for (int k = 0; k < 4; k++) {
        int idx = k * 256 + t;                 // 1024 float4: row idx>>4, col4 idx&15
        float4 v = cb4[(idx >> 4) * 256 + (idx & 15)];
        mx = fmaxf(mx, fmaxf(fmaxf(v.x, v.y), fmaxf(v.z, v.w)));
    }
    #pragma unroll
    for (int m = 1; m < 64; m <<= 1) mx = fmaxf(mx, __shfl_xor(mx, m, 64));
    if ((t & 63) == 0) wmax[t >> 6] = mx;
    __syncthreads();
    float tmax = fmaxf(fmaxf(wmax[0], wmax[1]), fmaxf(wmax[2], wmax[3]));
    if (tmax <= 2.0f) return;

    // slow path: full separable pooling on the 95x95 halo
    for (int idx = t; idx < 95 * 95; idx += 256) {
        int r = idx / 95, c = idx - r * 95;
        int gr = i0 - 16 + r, gc = j0 - 16 + c;
        float v = -3.4e38f;
        if ((unsigned)gr < 1024u && (unsigned)gc < 1024u) v = result[gr * 1024 + gc];
        ls[r * 96 + c] = v;
    }
    __syncthreads();
    for (int idx = t; idx < 95 * 64; idx += 256) {
        int r = idx >> 6, c = idx & 63;
        const float* p = ls + r * 96 + c;
        float m = p[0];
        #pragma unroll
        for (int d = 1; d < 32; d++) m = fmaxf(m, p[d]);
        hr[idx] = m;
    }
    __syncthreads();
    for (int idx = t; idx < 64 * 64; idx += 256) {
        int r = idx >> 6, c = idx & 63;
        const float* p = hr + r * 64 + c;
        float m = p[0];
        #pragma unroll
        for (int d = 1; d < 32; d++) m = fmaxf(m, p[d * 64]);
        float v = ls[(r + 16) * 96 + (c + 16)];
        int gi = i0 + r, gj = j0 + c;
        if (gi >= 1 && gj >= 1 && v > 2.0f && v == m) {
            unsigned int k = atomicAdd(cnt, 1u);
            if (k < 2048)
                cand[k] = ((unsigned long long)__float_as_uint(v) << 32)
                        | (unsigned int)(~(unsigned int)(gi * 1024 + gj));
        }
    }
}

// sort candidates (value desc, index asc) and emit outputs; empty fast path
__global__ __launch_bounds__(1024) void k_final(
    const float* __restrict__ image, const unsigned int* __restrict__ cnt,
    const unsigned long long* __restrict__ cand, float* __restrict__ out) {
    __shared__ unsigned long long keys[2048];
    int t = threadIdx.x;
    int n = (int)cnt[0]; if (n > 2048) n = 2048;
    if (n == 0) return;                         // d_out already zeroed by k_pex
    for (int k = t; k < 2048; k += 1024) keys[k] = (k < n) ? cand[k] : 0ull;
    __syncthreads();
    for (int size = 2; size <= 2048; size <<= 1) {
        for (int stride = size >> 1; stride > 0; stride >>= 1) {
            for (int i = t; i < 2048; i += 1024) {
                int ixj = i ^ stride;
                if (ixj > i) {
                    unsigned long long a = keys[i], b = keys[ixj];
                    bool sw = ((i & size) == 0) ? (a < b) : (a > b);  // descending
                    if (sw) { keys[i] = b; keys[ixj] = a; }
                }
            }
            __syncthreads();
        }
    }
    float* roipos = out;
    float* intensity = out + 2048;
    float* rois = out + 3072;
    float* validf = out + 3072 + 1048576;
    int nw = n < 1024 ? n : 1024;
    if (t < nw) {
        unsigned long long key = keys[t];
        float val = __uint_as_float((unsigned int)(key >> 32));
        unsigned int p = ~(unsigned int)key;
        int y = (int)(p >> 10), x = (int)(p & 1023);
        int roy = y - 16, rox = x - 16;
        bool valid = (roy >= 0 && roy < 992 && rox >= 0 && rox < 992);
        int royc = roy < 0 ? 0 : (roy > 992 ? 992 : roy);
        int roxc = rox < 0 ? 0 : (rox > 992 ? 992 : rox);
        roipos[2 * t]     = valid ? (float)royc : 0.f;
        roipos[2 * t + 1] = valid ? (float)roxc : 0.f;
        intensity[t]      = valid ? val : 0.f;
        validf[t]         = valid ? 1.f : 0.f;
    }
    __syncthreads();
    for (int k = 0; k < nw; k++) {
        unsigned long long key = keys[k];
        unsigned int p = ~(unsigned int)key;
        int y = (int)(p >> 10), x = (int)(p & 1023);
        int roy = y - 16, rox = x - 16;
        if (!(roy >= 0 && roy < 992 && rox >= 0 && rox < 992)) continue;
        int u = t >> 5, vv = t & 31;
        rois[k * 1024 + t] = image[(roy + u) * 1024 + (rox + vv)];
    }
}

extern "C" void kernel_launch(void* const* d_in, const int* in_sizes, int n_in,
                              void* d_out, int out_size, void* d_ws, size_t ws_size,
                              hipStream_t stream) {
    const float* image = (const float*)d_in[0];
    const float* psf   = (const float*)d_in[1];
    float* out = (float*)d_out;
    char* ws = (char*)d_ws;
    unsigned char* img8  = (unsigned char*)(ws + WS_IMG8);
    unsigned char* bfrag = (unsigned char*)(ws + WS_BFRAG);
    float* pex = (float*)(ws + WS_PEX);
    float* result = (float*)(ws + WS_RESULT);
    unsigned int* cnt = (unsigned int*)(ws + WS_CAND);
    unsigned long long* cand = (unsigned long long*)(ws + WS_CAND + 16);

    int n4 = out_size / 4;
    hipLaunchKernelGGL(k_pex,     dim3(2144), dim3(256), 0, stream,
                       image, pex, (uint32_t*)img8, psf, bfrag, cnt, (float4*)d_out, n4);
    hipLaunchKernelGGL(k_conv,    dim3(512),  dim3(512), 0, stream,
                       (const unsigned long long*)img8, bfrag, pex, result);
    hipLaunchKernelGGL(k_maxcand, dim3(256),  dim3(256), 0, stream, result, cnt, cand);
    hipLaunchKernelGGL(k_final,   dim3(1),    dim3(1024), 0, stream, image, cnt, cand, out);
}

// Round 14
// 115.850 us; speedup vs baseline: 1.0592x; 1.0592x over previous
//
#include <hip/hip_runtime.h>
#include <stdint.h>

typedef float v4f __attribute__((ext_vector_type(4)));
typedef int   v8i __attribute__((ext_vector_type(8)));
typedef unsigned long long u64;

#define PEX_STRIDE 1156
#define WS_IMG8   0
#define WS_BFRAG  1048576
#define WS_PEX    1064960
#define WS_RESULT 9994240
#define WS_CAND   14188544

__device__ inline unsigned char f32_to_e4m3(float v) {
    if (!(v > 0.0f)) return 0;
    if (v >= 448.0f) return 0x7e;
    if (v < 0.015625f) {                       // subnormal: m * 2^-9
        int m = (int)(v * 512.0f + 0.5f);
        if (m > 7) return 0x08;
        return (unsigned char)m;
    }
    unsigned int u = __float_as_uint(v) + 0x00080000u;  // round into bit 20
    int e = (int)((u >> 23) & 0xff) - 127;
    int m3 = (int)(u >> 20) & 7;
    int e8 = e + 7;
    if (e8 >= 16) return 0x7e;
    return (unsigned char)((e8 << 3) | m3);
}

// Fused front kernel.
// blocks [0,1024): wrapped row prefix sums + fp8 image emit (row L1-hot)
// blocks [1024,2080): zero d_out
// blocks [2080,2144): A-fragment psf table for the K=128 MX MFMA:
//   abuf[kb4][lane][b] fp8 = psf[z][a][b]*cos(2pi(a+b-32)/1024)*1024,
//   z=lane&15, a=4*kb4+(lane>>4), b=0..31; also zeroes cnt[0].
__global__ void k_pex(const float* __restrict__ img, float* __restrict__ pex,
                      uint32_t* __restrict__ img8, const float* __restrict__ psf,
                      unsigned char* __restrict__ bf, unsigned int* cnt,
                      float4* __restrict__ out, int n4) {
    __shared__ float wtot[4];
    int blk = blockIdx.x, t = threadIdx.x;
    if (blk >= 1024) {
        if (blk < 2080) {
            int i = (blk - 1024) * 256 + t;
            if (i < n4) { float4 z; z.x = z.y = z.z = z.w = 0.f; out[i] = z; }
        } else {
            int u = (blk - 2080) * 256 + t;   // 16384 = 8 kb4 x 64 lanes x 32 B
            if (u == 0) cnt[0] = 0u;
            int kb4 = u >> 11; int l = (u >> 5) & 63; int b = u & 31;
            int z = l & 15; int a = kb4 * 4 + (l >> 4);
            float p = psf[z * 1024 + a * 32 + b];
            float c = cosf((float)(a + b - 32) * (6.283185307179586f / 1024.0f));
            bf[u] = f32_to_e4m3(p * c * 1024.0f);
        }
        return;
    }
    int r = blk;
    const float* row = img + r * 1024;
    float s[5];
    float acc = 0.f;
    int base = t * 5;
    #pragma unroll
    for (int j = 0; j < 5; j++) {
        int c = base + j;
        float v = (c < 1152) ? row[(c - 64) & 1023] : 0.f;
        acc += v; s[j] = acc;
    }
    float sc = acc;
    int lane = t & 63, w = t >> 6;
    #pragma unroll
    for (int off = 1; off < 64; off <<= 1) {
        float v = __shfl_up(sc, off, 64);
        if (lane >= off) sc += v;
    }
    if (lane == 63) wtot[w] = sc;
    __syncthreads();
    float wbase = 0.f;
    #pragma unroll
    for (int i = 0; i < 3; i++) if (i < w) wbase += wtot[i];
    float excl = wbase + (sc - acc);
    float* prow = pex + r * PEX_STRIDE;
    if (t == 0) prow[0] = 0.f;
    #pragma unroll
    for (int j = 0; j < 5; j++) {
        int c = base + j;
        if (c < 1152) prow[c + 1] = excl + s[j];
    }
    float4 v4 = *(const float4*)(row + 4 * t);
    img8[r * 256 + t] = (uint32_t)f32_to_e4m3(v4.x)
                      | ((uint32_t)f32_to_e4m3(v4.y) << 8)
                      | ((uint32_t)f32_to_e4m3(v4.z) << 16)
                      | ((uint32_t)f32_to_e4m3(v4.w) << 24);
}

// build MX MFMA B operand from 4 u64 (constant-index inserts: register-only)
__device__ inline v8i packb(u64 a, u64 b, u64 c, u64 d) {
    v8i v;
    v[0] = (int)(unsigned int)a;  v[1] = (int)(unsigned int)(a >> 32);
    v[2] = (int)(unsigned int)b;  v[3] = (int)(unsigned int)(b >> 32);
    v[4] = (int)(unsigned int)c;  v[5] = (int)(unsigned int)(c >> 32);
    v[6] = (int)(unsigned int)d;  v[7] = (int)(unsigned int)(d >> 32);
    return v;
}

__device__ inline float redz(v4f a) {   // z-max over 16 z (4 regs + cross-g)
    float m = fmaxf(fmaxf(a.x, a.y), fmaxf(a.z, a.w));
    m = fmaxf(m, __shfl_xor(m, 16, 64));
    m = fmaxf(m, __shfl_xor(m, 32, 64));
    return m;
}

// K-loop for one sh-half (SH0 = 0 or 4): compile-time funnel shifts.
// Per kb4: one 6-u64 window read from single-copy LDS, 4 sh x 2 MFMAs.
template<int SH0>
__device__ __forceinline__ void kloop(const ulonglong2* __restrict__ smv,
                                      int i0, int nn, int g, int h,
                                      const v8i* __restrict__ bfA,
                                      v4f acc0[4], v4f acc1[4]) {
    #pragma unroll
    for (int kb4 = 0; kb4 < 8; kb4++) {
        int lr = i0 + nn + g + 4 * kb4;       // local staged row 0..94
        const ulonglong2* rp = smv + lr * 5 + h;
        ulonglong2 p0 = rp[0], p1 = rp[1], p2 = rp[2];
        u64 w0 = p0.x, w1 = p0.y, w2 = p1.x, w3 = p1.y, w4 = p2.x, w5 = p2.y;
        v8i av = bfA[kb4 << 6];               // bfrag + kb4*2048 + lane*32
        #pragma unroll
        for (int s = 0; s < 4; s++) {
            const int sh = SH0 + s;
            u64 S0, S1, S2, S3, S4;
            if (sh == 0) { S0 = w0; S1 = w1; S2 = w2; S3 = w3; S4 = w4; }
            else {
                const int sb = 8 * sh;
                S0 = (w0 >> sb) | (w1 << (64 - sb));
                S1 = (w1 >> sb) | (w2 << (64 - sb));
                S2 = (w2 >> sb) | (w3 << (64 - sb));
                S3 = (w3 >> sb) | (w4 << (64 - sb));
                S4 = (w4 >> sb) | (w5 << (64 - sb));
            }
            acc0[s] = __builtin_amdgcn_mfma_scale_f32_16x16x128_f8f6f4(
                    av, packb(S0, S1, S2, S3), acc0[s], 0, 0, 0,
                    0x7f7f7f7f, 0, 0x7f7f7f7f);
            acc1[s] = __builtin_amdgcn_mfma_scale_f32_16x16x128_f8f6f4(
                    av, packb(S1, S2, S3, S4), acc1[s], 0, 0, 0,
                    0x7f7f7f7f, 0, 0x7f7f7f7f);
        }
    }
}

// MFMA conv (MX fp8 K=128): single-copy LDS staging + register funnels,
// LOW-LIVE-STATE split. r13 PMC: 16 live accs + window -> allocator spilled
// (VGPR 72, WRITE 11MB). r10 precedent: 16 accs alone = 88 VGPR no spill.
// Fix: 1024 thr = 16 waves = 4 rowgrps x 2 col-halves(h) x 2 sh-halves(s2);
// per wave only 8 accs (32 VGPR) + 12 window + temps ~= 90 VGPR. sh-half via
// wave-uniform branch into template<SH0> kloop (funnels stay compile-time).
// Per block: 760 u64 staged once, 384 b128 window reads, 1024 MFMAs.
__global__ __launch_bounds__(1024) void k_conv(
    const unsigned long long* __restrict__ img64,
    const unsigned char* __restrict__ bfrag,
    const float* __restrict__ pex, float* __restrict__ result) {
    __shared__ ulonglong2 smv[95 * 5];     // [row][5x16B]; u64 0..7 used, 8..9 pad
    __shared__ float rbp[8][5][16];
    __shared__ float rbv[8][5];
    int tid = threadIdx.x;
    int wave = tid >> 6, lane = tid & 63;
    int b = blockIdx.x;
    int tr = b >> 5, tc = b & 31;
    int r0 = tr * 64, c0 = tc * 32;

    // fused bg partial sums (disk r=64 mean via pex prefix): 8x8 rows x 5
    // sampled cols = 40 lanes, dy-chunk of 8 per wave; j==127 predicated off.
    if (lane < 40) {
        int si = lane / 5, kc = lane - si * 5;
        int baserow = r0 + si * 8 + 3;
        int n = c0 + 8 * kc;
        int j0 = wave * 8;
        float acc = 0.f;
        #pragma unroll
        for (int u = 0; u < 8; u++) {
            int j = j0 + u;
            if (j < 127) {
                int dy = j - 63;
                int ady = dy < 0 ? -dy : dy;
                int w = (int)sqrtf((float)(4095 - ady * ady));
                const float* p = pex + ((baserow + dy) & 1023) * PEX_STRIDE + n;
                acc += p[65 + w] - p[64 - w];
            }
        }
        rbp[si][kc][wave] = acc;
    }

    // staging: 95 rows x 8 u64, single copy, one pass over 1024 threads
    u64* smq = (u64*)smv;
    if (tid < 760) {
        int dr = tid >> 3, j = tid & 7;
        int row = (r0 + dr - 16) & 1023;
        int cbyte = (c0 - 16 + 8 * j) & 1023;
        smq[dr * 10 + j] = img64[row * 128 + (cbyte >> 3)];
    }
    __syncthreads();
    if (tid < 40) {
        int si = tid / 5, kc = tid - si * 5;
        float s = 0.f;
        #pragma unroll
        for (int hh = 0; hh < 16; hh++) s += rbp[si][kc][hh];
        const float kk = (float)(1.0 / (3.14159265358979323846 * 4096.0));
        rbv[si][kc] = 1.0f / ((s * kk + 1.0f) * 1024.0f);  // /1024 undoes psf scale
    }

    int rg = wave >> 2;                       // row group 0..3
    int h  = (wave >> 1) & 1;                 // col half (16-byte window offset)
    int s2 = wave & 1;                        // sh half: sh in {4*s2..4*s2+3}
    int i0 = rg * 16;
    int nn = lane & 15, g = lane >> 4;
    const v8i* bfA = (const v8i*)(bfrag + lane * 32);   // A rows for this lane

    v4f acc0[4], acc1[4];
    #pragma unroll
    for (int s = 0; s < 4; s++) { acc0[s] = (v4f)0.f; acc1[s] = (v4f)0.f; }

    if (s2 == 0) kloop<0>(smv, i0, nn, g, h, bfA, acc0, acc1);
    else         kloop<4>(smv, i0, nn, g, h, bfA, acc0, acc1);

    float zm0[4], zm1[4];
    #pragma unroll
    for (int s = 0; s < 4; s++) { zm0[s] = redz(acc0[s]); zm1[s] = redz(acc1[s]); }
    __syncthreads();   // rbv ready

    // epilogue: lane (nn,g) stores 2 cols: uu0 = 16h + 8*(g>>1) + 4*s2 + 2*(g&1)
    // acc0 covers cols 16h+4s2+s (s=sh-SH0), acc1 covers +8.
    int sil = (i0 + nn) >> 3;
    int uu0 = 16 * h + ((g >> 1) << 3) + (s2 << 2) + ((g & 1) << 1);
    float ov[2];
    #pragma unroll
    for (int dt = 0; dt < 2; dt++) {
        int uu = uu0 + dt;
        int kc = uu >> 3;
        float fr = (float)(uu & 7) * 0.125f;
        float za = (g & 1) ? zm0[2 + dt] : zm0[dt];
        float zb = (g & 1) ? zm1[2 + dt] : zm1[dt];
        float z = (g & 2) ? zb : za;
        float rv0 = rbv[sil][kc], rv1 = rbv[sil][kc + 1];
        ov[dt] = z * (rv0 + fr * (rv1 - rv0));
    }
    float2 o; o.x = ov[0]; o.y = ov[1];
    *(float2*)(result + (r0 + i0 + nn) * 1024 + c0 + uu0) = o;
}

// fused 32x32 stride-1 maxpool + candidate extraction, with fast reject.
__global__ __launch_bounds__(256) void k_maxcand(const float* __restrict__ result,
                                                 unsigned int* cnt,
                                                 unsigned long long* cand) {
    __shared__ float ls[95 * 96];
    __shared__ float hr[95 * 64];
    __shared__ float wmax[4];
    int bx = blockIdx.x & 15, by = blockIdx.x >> 4;
    int i0 = by * 64, j0 = bx * 64;
    int t = threadIdx.x;
    // fast reject: tile max over the 64x64 core (float4 loads)
    const float4* cb4 = (const float4*)(result + i0 * 1024 + j0);
    float mx = -3.4e38f;
    #pragma unroll
    for (int k = 0; k < 4; k++) {
        int idx = k * 256 + t;                 // 1024 float4: row idx>>4, col4 idx&15
        float4 v = cb4[(idx >> 4) * 256 + (idx & 15)];
        mx = fmaxf(mx, fmaxf(fmaxf(v.x, v.y), fmaxf(v.z, v.w)));
    }
    #pragma unroll
    for (int m = 1; m < 64; m <<= 1) mx = fmaxf(mx, __shfl_xor(mx, m, 64));
    if ((t & 63) == 0) wmax[t >> 6] = mx;
    __syncthreads();
    float tmax = fmaxf(fmaxf(wmax[0], wmax[1]), fmaxf(wmax[2], wmax[3]));
    if (tmax <= 2.0f) return;

    // slow path: full separable pooling on the 95x95 halo
    for (int idx = t; idx < 95 * 95; idx += 256) {
        int r = idx / 95, c = idx - r * 95;
        int gr = i0 - 16 + r, gc = j0 - 16 + c;
        float v = -3.4e38f;
        if ((unsigned)gr < 1024u && (unsigned)gc < 1024u) v = result[gr * 1024 + gc];
        ls[r * 96 + c] = v;
    }
    __syncthreads();
    for (int idx = t; idx < 95 * 64; idx += 256) {
        int r = idx >> 6, c = idx & 63;
        const float* p = ls + r * 96 + c;
        float m = p[0];
        #pragma unroll
        for (int d = 1; d < 32; d++) m = fmaxf(m, p[d]);
        hr[idx] = m;
    }
    __syncthreads();
    for (int idx = t; idx < 64 * 64; idx += 256) {
        int r = idx >> 6, c = idx & 63;
        const float* p = hr + r * 64 + c;
        float m = p[0];
        #pragma unroll
        for (int d = 1; d < 32; d++) m = fmaxf(m, p[d * 64]);
        float v = ls[(r + 16) * 96 + (c + 16)];
        int gi = i0 + r, gj = j0 + c;
        if (gi >= 1 && gj >= 1 && v > 2.0f && v == m) {
            unsigned int k = atomicAdd(cnt, 1u);
            if (k < 2048)
                cand[k] = ((unsigned long long)__float_as_uint(v) << 32)
                        | (unsigned int)(~(unsigned int)(gi * 1024 + gj));
        }
    }
}

// sort candidates (value desc, index asc) and emit outputs; empty fast path
__global__ __launch_bounds__(1024) void k_final(
    const float* __restrict__ image, const unsigned int* __restrict__ cnt,
    const unsigned long long* __restrict__ cand, float* __restrict__ out) {
    __shared__ unsigned long long keys[2048];
    int t = threadIdx.x;
    int n = (int)cnt[0]; if (n > 2048) n = 2048;
    if (n == 0) return;                         // d_out already zeroed by k_pex
    for (int k = t; k < 2048; k += 1024) keys[k] = (k < n) ? cand[k] : 0ull;
    __syncthreads();
    for (int size = 2; size <= 2048; size <<= 1) {
        for (int stride = size >> 1; stride > 0; stride >>= 1) {
            for (int i = t; i < 2048; i += 1024) {
                int ixj = i ^ stride;
                if (ixj > i) {
                    unsigned long long a = keys[i], b = keys[ixj];
                    bool sw = ((i & size) == 0) ? (a < b) : (a > b);  // descending
                    if (sw) { keys[i] = b; keys[ixj] = a; }
                }
            }
            __syncthreads();
        }
    }
    float* roipos = out;
    float* intensity = out + 2048;
    float* rois = out + 3072;
    float* validf = out + 3072 + 1048576;
    int nw = n < 1024 ? n : 1024;
    if (t < nw) {
        unsigned long long key = keys[t];
        float val = __uint_as_float((unsigned int)(key >> 32));
        unsigned int p = ~(unsigned int)key;
        int y = (int)(p >> 10), x = (int)(p & 1023);
        int roy = y - 16, rox = x - 16;
        bool valid = (roy >= 0 && roy < 992 && rox >= 0 && rox < 992);
        int royc = roy < 0 ? 0 : (roy > 992 ? 992 : roy);
        int roxc = rox < 0 ? 0 : (rox > 992 ? 992 : rox);
        roipos[2 * t]     = valid ? (float)royc : 0.f;
        roipos[2 * t + 1] = valid ? (float)roxc : 0.f;
        intensity[t]      = valid ? val : 0.f;
        validf[t]         = valid ? 1.f : 0.f;
    }
    __syncthreads();
    for (int k = 0; k < nw; k++) {
        unsigned long long key = keys[k];
        unsigned int p = ~(unsigned int)key;
        int y = (int)(p >> 10), x = (int)(p & 1023);
        int roy = y - 16, rox = x - 16;
        if (!(roy >= 0 && roy < 992 && rox >= 0 && rox < 992)) continue;
        int u = t >> 5, vv = t & 31;
        rois[k * 1024 + t] = image[(roy + u) * 1024 + (rox + vv)];
    }
}

extern "C" void kernel_launch(void* const* d_in, const int* in_sizes, int n_in,
                              void* d_out, int out_size, void* d_ws, size_t ws_size,
                              hipStream_t stream) {
    const float* image = (const float*)d_in[0];
    const float* psf   = (const float*)d_in[1];
    float* out = (float*)d_out;
    char* ws = (char*)d_ws;
    unsigned char* img8  = (unsigned char*)(ws + WS_IMG8);
    unsigned char* bfrag = (unsigned char*)(ws + WS_BFRAG);
    float* pex = (float*)(ws + WS_PEX);
    float* result = (float*)(ws + WS_RESULT);
    unsigned int* cnt = (unsigned int*)(ws + WS_CAND);
    unsigned long long* cand = (unsigned long long*)(ws + WS_CAND + 16);

    int n4 = out_size / 4;
    hipLaunchKernelGGL(k_pex,     dim3(2144), dim3(256), 0, stream,
                       image, pex, (uint32_t*)img8, psf, bfrag, cnt, (float4*)d_out, n4);
    hipLaunchKernelGGL(k_conv,    dim3(512),  dim3(1024), 0, stream,
                       (const unsigned long long*)img8, bfrag, pex, result);
    hipLaunchKernelGGL(k_maxcand, dim3(256),  dim3(256), 0, stream, result, cnt, cand);
    hipLaunchKernelGGL(k_final,   dim3(1),    dim3(1024), 0, stream, image, cnt, cand, out);
}

// Round 15
// 104.776 us; speedup vs baseline: 1.1712x; 1.1057x over previous
//
#include <hip/hip_runtime.h>
#include <stdint.h>

typedef float v4f __attribute__((ext_vector_type(4)));
typedef int   v8i __attribute__((ext_vector_type(8)));
typedef unsigned long long u64;

#define PEX_STRIDE 1156
#define CSTRIDE 950   // u64 per shifted copy: 95 rows x 10 (8 slots + 2 pad, even for b128)
#define WS_IMG8   0                 // 8 pre-shifted copies, 1MB each
#define WS_BFRAG  8388608
#define WS_PEX    8404992
#define WS_RESULT 13139968
#define WS_CAND   17334272

__device__ inline unsigned char f32_to_e4m3(float v) {
    if (!(v > 0.0f)) return 0;
    if (v >= 448.0f) return 0x7e;
    if (v < 0.015625f) {                       // subnormal: m * 2^-9
        int m = (int)(v * 512.0f + 0.5f);
        if (m > 7) return 0x08;
        return (unsigned char)m;
    }
    unsigned int u = __float_as_uint(v) + 0x00080000u;  // round into bit 20
    int e = (int)((u >> 23) & 0xff) - 127;
    int m3 = (int)(u >> 20) & 7;
    int e8 = e + 7;
    if (e8 >= 16) return 0x7e;
    return (unsigned char)((e8 << 3) | m3);
}

// Fused front kernel.
// blocks [0,1024): wrapped row prefix sums + fp8 image emit as 8 PRE-SHIFTED
//   copies: copy s, u64 j of row r = bytes [8j+s .. 8j+s+7] (mod 1024) of the
//   packed fp8 row. Moves the byte-alignment tax (paid per-conv-block in LDS
//   or VALU in r2-r14) to ONE global pass: +7MB coalesced writes (~1.5us).
// blocks [1024,2080): zero d_out
// blocks [2080,2144): A-fragment psf table for the K=128 MX MFMA (as before).
__global__ void k_pex(const float* __restrict__ img, float* __restrict__ pex,
                      u64* __restrict__ img8s, const float* __restrict__ psf,
                      unsigned char* __restrict__ bf, unsigned int* cnt,
                      float4* __restrict__ out, int n4) {
    __shared__ float wtot[4];
    __shared__ uint32_t rowpk[256];
    int blk = blockIdx.x, t = threadIdx.x;
    if (blk >= 1024) {
        if (blk < 2080) {
            int i = (blk - 1024) * 256 + t;
            if (i < n4) { float4 z; z.x = z.y = z.z = z.w = 0.f; out[i] = z; }
        } else {
            int u = (blk - 2080) * 256 + t;   // 16384 = 8 kb4 x 64 lanes x 32 B
            if (u == 0) cnt[0] = 0u;
            int kb4 = u >> 11; int l = (u >> 5) & 63; int b = u & 31;
            int z = l & 15; int a = kb4 * 4 + (l >> 4);
            float p = psf[z * 1024 + a * 32 + b];
            float c = cosf((float)(a + b - 32) * (6.283185307179586f / 1024.0f));
            bf[u] = f32_to_e4m3(p * c * 1024.0f);
        }
        return;
    }
    int r = blk;
    const float* row = img + r * 1024;
    // pack 4 fp8 bytes early so rowpk is covered by the same barrier as wtot
    float4 v4 = *(const float4*)(row + 4 * t);
    uint32_t pk = (uint32_t)f32_to_e4m3(v4.x)
                | ((uint32_t)f32_to_e4m3(v4.y) << 8)
                | ((uint32_t)f32_to_e4m3(v4.z) << 16)
                | ((uint32_t)f32_to_e4m3(v4.w) << 24);
    rowpk[t] = pk;

    float s[5];
    float acc = 0.f;
    int base = t * 5;
    #pragma unroll
    for (int j = 0; j < 5; j++) {
        int c = base + j;
        float v = (c < 1152) ? row[(c - 64) & 1023] : 0.f;
        acc += v; s[j] = acc;
    }
    float sc = acc;
    int lane = t & 63, w = t >> 6;
    #pragma unroll
    for (int off = 1; off < 64; off <<= 1) {
        float v = __shfl_up(sc, off, 64);
        if (lane >= off) sc += v;
    }
    if (lane == 63) wtot[w] = sc;
    __syncthreads();
    float wbase = 0.f;
    #pragma unroll
    for (int i = 0; i < 3; i++) if (i < w) wbase += wtot[i];
    float excl = wbase + (sc - acc);
    float* prow = pex + r * PEX_STRIDE;
    if (t == 0) prow[0] = 0.f;
    #pragma unroll
    for (int j = 0; j < 5; j++) {
        int c = base + j;
        if (c < 1152) prow[c + 1] = excl + s[j];
    }
    // emit 8 shifted copies: thread t -> copy s = t>>5, u64s j = (t&31)*4 + i
    {
        int scp = t >> 5;
        int j4 = (t & 31) * 4;
        int sb = 8 * (scp & 3);
        int wo = scp >> 2;                    // extra word offset for s>=4
        #pragma unroll
        for (int i = 0; i < 4; i++) {
            int j = j4 + i;
            int w0 = (2 * j + wo) & 255;
            int w1 = (2 * j + wo + 1) & 255;
            int w2 = (2 * j + wo + 2) & 255;
            u64 lo = ((u64)rowpk[w1] << 32) | (u64)rowpk[w0];
            u64 val = sb ? ((lo >> sb) | ((u64)rowpk[w2] << (64 - sb))) : lo;
            img8s[((size_t)scp << 17) + r * 128 + j] = val;
        }
    }
}

// 32-byte LDS fragment load (8B-aligned) -> v8i for the MX MFMA B operand.
// Built via constant-index element inserts: guaranteed register-only.
__device__ inline v8i ldsB(const u64* p) {
    u64 q0 = p[0], q1 = p[1], q2 = p[2], q3 = p[3];
    v8i v;
    v[0] = (int)(unsigned int)q0;  v[1] = (int)(unsigned int)(q0 >> 32);
    v[2] = (int)(unsigned int)q1;  v[3] = (int)(unsigned int)(q1 >> 32);
    v[4] = (int)(unsigned int)q2;  v[5] = (int)(unsigned int)(q2 >> 32);
    v[6] = (int)(unsigned int)q3;  v[7] = (int)(unsigned int)(q3 >> 32);
    return v;
}

// MFMA conv (MX-scaled fp8, K=128 = 4 psf rows) with FUSED background.
// Compute loop = the proven r7 structure (session best 95.9us), stride 9->10.
// Staging now COPIES pre-shifted global data as b128 pairs: 3040 ds_write_b128
// (vs r7's 5320 ds_write_b64 + per-block shift ALU) — no funnels, no shifts.
__global__ __launch_bounds__(512, 4) void k_conv(
    const u64* __restrict__ img64,
    const unsigned char* __restrict__ bfrag,
    const float* __restrict__ pex, float* __restrict__ result) {
    __shared__ ulonglong2 smv2[8 * 475];             // 60800 B, 16B-aligned
    __shared__ float rbp[8][5][8];
    __shared__ float rbv[8][5];
    u64* sm = (u64*)smv2;
    int tid = threadIdx.x;
    int wave = tid >> 6, lane = tid & 63;
    int b = blockIdx.x;
    int tr = b >> 5, tc = b & 31;
    int r0 = tr * 64, c0 = tc * 32;

    // fused bg partial sums first (r7): lane (si,kc), dy-chunk = wave,
    // fully unrolled; j==127 predicated off for wave 7.
    if (lane < 40) {
        int si = lane / 5, kc = lane - si * 5;
        int baserow = r0 + si * 8 + 3;
        int n = c0 + 8 * kc;
        int j0 = wave * 16;
        float acc = 0.f;
        #pragma unroll
        for (int u = 0; u < 16; u++) {
            int j = j0 + u;
            if (j < 127) {
                int dy = j - 63;
                int ady = dy < 0 ? -dy : dy;
                int w = (int)sqrtf((float)(4095 - ady * ady));
                const float* p = pex + ((baserow + dy) & 1023) * PEX_STRIDE + n;
                acc += p[65 + w] - p[64 - w];
            }
        }
        rbp[si][kc][wave] = acc;
    }

    // staging: 8 copies x 95 rows x 4 b128 pairs (slots 0..7; reads use 0..6).
    // source = pre-shifted copy s: u64 j covers bytes 8j+s of the row.
    for (int u = tid; u < 3040; u += 512) {
        int s = u / 380, rem = u - s * 380;   // 380 = 95*4
        int dr = rem >> 2, p = rem & 3;
        int row = (r0 + dr - 16) & 1023;
        int B0 = (c0 - 16 + 16 * p) & 1023;   // byte pos of first u64 (mult of 8)
        int B1 = (B0 + 8) & 1023;
        const u64* cp = img64 + ((size_t)s << 17) + row * 128;
        ulonglong2 pr;
        pr.x = cp[B0 >> 3];
        pr.y = cp[B1 >> 3];
        *((ulonglong2*)(sm + s * CSTRIDE + dr * 10) + p) = pr;
    }
    __syncthreads();
    if (tid < 40) {
        int si = tid / 5, kc = tid - si * 5;
        float s = 0.f;
        #pragma unroll
        for (int h = 0; h < 8; h++) s += rbp[si][kc][h];
        const float kk = (float)(1.0 / (3.14159265358979323846 * 4096.0));
        rbv[si][kc] = 1.0f / ((s * kk + 1.0f) * 1024.0f);  // /1024 undoes psf scale
    }

    int i0 = (wave >> 1) * 16;                // tile row group
    int cw = (wave & 1) * 16;                 // col half
    int q = lane >> 4;                        // K-block row offset (and C row grp)
    int n = lane & 15;
    // B-fragment base: bytes (cw+n)..(cw+n+31) of patch row (i0+q+cc+4*kb4),
    // from shifted copy (n&7), 4 consecutive u64 slots.
    const u64* bpq = sm + (n & 7) * CSTRIDE + ((cw + n) >> 3) + (i0 + q) * 10;
    const v8i* bfA = (const v8i*)(bfrag + lane * 32);   // A rows for this lane

    float zmax[16];
    #pragma unroll
    for (int h = 0; h < 2; h++) {
        #pragma unroll
        for (int p = 0; p < 4; p++) {
            const u64* tp = bpq + (h * 8 + p) * 10;
            v4f a0 = (v4f)0.0f, a1 = (v4f)0.0f;
            v8i bcur = ldsB(tp);
            #pragma unroll
            for (int kb4 = 0; kb4 < 8; kb4++) {
                v8i bnxt = ldsB(tp + (4 * (kb4 + 1)) * 10);
                v8i av = bfA[kb4 << 6];       // bfrag + kb4*2048 + lane*32
                a0 = __builtin_amdgcn_mfma_scale_f32_16x16x128_f8f6f4(
                        av, bcur, a0, 0, 0, 0, 0x7f7f7f7f, 0, 0x7f7f7f7f);
                a1 = __builtin_amdgcn_mfma_scale_f32_16x16x128_f8f6f4(
                        av, bnxt, a1, 0, 0, 0, 0x7f7f7f7f, 0, 0x7f7f7f7f);
                bcur = bnxt;
            }
            // z-max in registers, wave-wide (C row = 4q+reg = z)
            float m0 = fmaxf(fmaxf(a0.x, a0.y), fmaxf(a0.z, a0.w));
            m0 = fmaxf(m0, __shfl_xor(m0, 16, 64));
            m0 = fmaxf(m0, __shfl_xor(m0, 32, 64));
            zmax[h * 8 + p] = m0;
            float m1 = fmaxf(fmaxf(a1.x, a1.y), fmaxf(a1.z, a1.w));
            m1 = fmaxf(m1, __shfl_xor(m1, 16, 64));
            m1 = fmaxf(m1, __shfl_xor(m1, 32, 64));
            zmax[h * 8 + p + 4] = m1;
            __builtin_amdgcn_sched_barrier(0);   // bound liveness to one chain
        }
    }
    __syncthreads();   // rbv written pre-MFMA by threads<40; make visible to all

    int uu = cw + n;                          // 0..31 within tile
    int kc = uu >> 3;
    float fr = (float)(uu & 7) * 0.125f;
    int gcol = c0 + uu;
    #pragma unroll
    for (int c4 = 0; c4 < 4; c4++) {
        float m01 = (q & 1) ? zmax[c4 * 4 + 1] : zmax[c4 * 4 + 0];
        float m23 = (q & 1) ? zmax[c4 * 4 + 3] : zmax[c4 * 4 + 2];
        float m = (q & 2) ? m23 : m01;
        int lrow = i0 + c4 * 4 + q;           // 0..63
        int sil = lrow >> 3;
        float rv0 = rbv[sil][kc], rv1 = rbv[sil][kc + 1];
        float rbl = rv0 + fr * (rv1 - rv0);
        result[(r0 + lrow) * 1024 + gcol] = m * rbl;
    }
}

// fused 32x32 stride-1 maxpool + candidate extraction, with fast reject.
__global__ __launch_bounds__(256) void k_maxcand(const float* __restrict__ result,
                                                 unsigned int* cnt,
                                                 unsigned long long* cand) {
    __shared__ float ls[95 * 96];
    __shared__ float hr[95 * 64];
    __shared__ float wmax[4];
    int bx = blockIdx.x & 15, by = blockIdx.x >> 4;
    int i0 = by * 64, j0 = bx * 64;
    int t = threadIdx.x;
    // fast reject: tile max over the 64x64 core (float4 loads)
    const float4* cb4 = (const float4*)(result + i0 * 1024 + j0);
    float mx = -3.4e38f;
    #pragma unroll
    for (int k = 0; k < 4; k++) {
        int idx = k * 256 + t;                 // 1024 float4: row idx>>4, col4 idx&15
        float4 v = cb4[(idx >> 4) * 256 + (idx & 15)];
        mx = fmaxf(mx, fmaxf(fmaxf(v.x, v.y), fmaxf(v.z, v.w)));
    }
    #pragma unroll
    for (int m = 1; m < 64; m <<= 1) mx = fmaxf(mx, __shfl_xor(mx, m, 64));
    if ((t & 63) == 0) wmax[t >> 6] = mx;
    __syncthreads();
    float tmax = fmaxf(fmaxf(wmax[0], wmax[1]), fmaxf(wmax[2], wmax[3]));
    if (tmax <= 2.0f) return;

    // slow path: full separable pooling on the 95x95 halo
    for (int idx = t; idx < 95 * 95; idx += 256) {
        int r = idx / 95, c = idx - r * 95;
        int gr = i0 - 16 + r, gc = j0 - 16 + c;
        float v = -3.4e38f;
        if ((unsigned)gr < 1024u && (unsigned)gc < 1024u) v = result[gr * 1024 + gc];
        ls[r * 96 + c] = v;
    }
    __syncthreads();
    for (int idx = t; idx < 95 * 64; idx += 256) {
        int r = idx >> 6, c = idx & 63;
        const float* p = ls + r * 96 + c;
        float m = p[0];
        #pragma unroll
        for (int d = 1; d < 32; d++) m = fmaxf(m, p[d]);
        hr[idx] = m;
    }
    __syncthreads();
    for (int idx = t; idx < 64 * 64; idx += 256) {
        int r = idx >> 6, c = idx & 63;
        const float* p = hr + r * 64 + c;
        float m = p[0];
        #pragma unroll
        for (int d = 1; d < 32; d++) m = fmaxf(m, p[d * 64]);
        float v = ls[(r + 16) * 96 + (c + 16)];
        int gi = i0 + r, gj = j0 + c;
        if (gi >= 1 && gj >= 1 && v > 2.0f && v == m) {
            unsigned int k = atomicAdd(cnt, 1u);
            if (k < 2048)
                cand[k] = ((unsigned long long)__float_as_uint(v) << 32)
                        | (unsigned int)(~(unsigned int)(gi * 1024 + gj));
        }
    }
}

// sort candidates (value desc, index asc) and emit outputs; empty fast path
__global__ __launch_bounds__(1024) void k_final(
    const float* __restrict__ image, const unsigned int* __restrict__ cnt,
    const unsigned long long* __restrict__ cand, float* __restrict__ out) {
    __shared__ unsigned long long keys[2048];
    int t = threadIdx.x;
    int n = (int)cnt[0]; if (n > 2048) n = 2048;
    if (n == 0) return;                         // d_out already zeroed by k_pex
    for (int k = t; k < 2048; k += 1024) keys[k] = (k < n) ? cand[k] : 0ull;
    __syncthreads();
    for (int size = 2; size <= 2048; size <<= 1) {
        for (int stride = size >> 1; stride > 0; stride >>= 1) {
            for (int i = t; i < 2048; i += 1024) {
                int ixj = i ^ stride;
                if (ixj > i) {
                    unsigned long long a = keys[i], b = keys[ixj];
                    bool sw = ((i & size) == 0) ? (a < b) : (a > b);  // descending
                    if (sw) { keys[i] = b; keys[ixj] = a; }
                }
            }
            __syncthreads();
        }
    }
    float* roipos = out;
    float* intensity = out + 2048;
    float* rois = out + 3072;
    float* validf = out + 3072 + 1048576;
    int nw = n < 1024 ? n : 1024;
    if (t < nw) {
        unsigned long long key = keys[t];
        float val = __uint_as_float((unsigned int)(key >> 32));
        unsigned int p = ~(unsigned int)key;
        int y = (int)(p >> 10), x = (int)(p & 1023);
        int roy = y - 16, rox = x - 16;
        bool valid = (roy >= 0 && roy < 992 && rox >= 0 && rox < 992);
        int royc = roy < 0 ? 0 : (roy > 992 ? 992 : roy);
        int roxc = rox < 0 ? 0 : (rox > 992 ? 992 : rox);
        roipos[2 * t]     = valid ? (float)royc : 0.f;
        roipos[2 * t + 1] = valid ? (float)roxc : 0.f;
        intensity[t]      = valid ? val : 0.f;
        validf[t]         = valid ? 1.f : 0.f;
    }
    __syncthreads();
    for (int k = 0; k < nw; k++) {
        unsigned long long key = keys[k];
        unsigned int p = ~(unsigned int)key;
        int y = (int)(p >> 10), x = (int)(p & 1023);
        int roy = y - 16, rox = x - 16;
        if (!(roy >= 0 && roy < 992 && rox >= 0 && rox < 992)) continue;
        int u = t >> 5, vv = t & 31;
        rois[k * 1024 + t] = image[(roy + u) * 1024 + (rox + vv)];
    }
}

extern "C" void kernel_launch(void* const* d_in, const int* in_sizes, int n_in,
                              void* d_out, int out_size, void* d_ws, size_t ws_size,
                              hipStream_t stream) {
    const float* image = (const float*)d_in[0];
    const float* psf   = (const float*)d_in[1];
    float* out = (float*)d_out;
    char* ws = (char*)d_ws;
    u64* img8s = (u64*)(ws + WS_IMG8);
    unsigned char* bfrag = (unsigned char*)(ws + WS_BFRAG);
    float* pex = (float*)(ws + WS_PEX);
    float* result = (float*)(ws + WS_RESULT);
    unsigned int* cnt = (unsigned int*)(ws + WS_CAND);
    unsigned long long* cand = (unsigned long long*)(ws + WS_CAND + 16);

    int n4 = out_size / 4;
    hipLaunchKernelGGL(k_pex,     dim3(2144), dim3(256), 0, stream,
                       image, pex, img8s, psf, bfrag, cnt, (float4*)d_out, n4);
    hipLaunchKernelGGL(k_conv,    dim3(512),  dim3(512), 0, stream,
                       img8s, bfrag, pex, result);
    hipLaunchKernelGGL(k_maxcand, dim3(256),  dim3(256), 0, stream, result, cnt, cand);
    hipLaunchKernelGGL(k_final,   dim3(1),    dim3(1024), 0, stream, image, cnt, cand, out);
}